// Round 6
// baseline (271.215 us; speedup 1.0000x reference)
//
#include <hip/hip_runtime.h>
#include <cstddef>
#include <cstring>

#define NN 50000
#define NNP 50048
#define NE 800000
#define D 128
#define NG 512
#define BN_EPS 1e-5f
#define RSZC 25000    // count: nodes per range (2 ranges, 100 KB dyn LDS)
#define RSZF 12500    // fill: nodes per range (4 ranges, 50 KB LDS)
#define NCHUNK 64
#define CSZ 12500     // edges per chunk

typedef __bf16 bf16_t;
typedef __bf16 bf16x8 __attribute__((ext_vector_type(8)));
typedef float f32x4 __attribute__((ext_vector_type(4)));

// ---- workspace layout (float offsets) ----
#define OFF_ACCN 0            // float[4*512]
#define OFF_ACCE 2048         // float[4*512]
#define ZERO_FLOATS 4096      // only the accumulators need zeroing
#define OFF_DIS  4096         // float[50048]
#define OFF_CNT  54144        // int[50048]
#define OFF_COLP 104192       // int[50048]
#define OFF_ENDS 154240       // int[50048]
#define OFF_BSUM 204288       // int[256]
#define OFF_BOFF 204544       // int[256]
#define OFF_T1   204800       // float[50048]
#define OFF_T2   254848       // float[50048]
#define OFF_BP   304896       // float[3*128 padded]
#define OFF_WPT  305408       // bf16[3*128*128] (24576 floats)
#define OFF_PR   329984       // int[64][50048] = 3203072
#define OFF_PC   3533056      // int[64][50048] = 3203072 (becomes CPS after colscan)
#define OFF_SRCS 6736128      // int[800000]
#define OFF_HBFA 7536128      // bf16[50048*128] (3203072 floats)
#define OFF_HBFB 10739200     // bf16[50048*128]
// hA32 (fp32 prop2 output) aliases the dead PR+PC region
#define OFF_HA32 OFF_PR       // 6406144 float slots available >= 6400000

// ---- output layout (float offsets in d_out) ----
#define O_NKEY 0
#define O_EKEY 50000
#define O_NKN  850000
#define O_NEN  850512
#define O_EKN  851024
#define O_EEN  851536
#define O_NZN  852048
#define O_NZE  852560

__device__ __forceinline__ float sigmoidf(float x) {
    return 1.0f / (1.0f + expf(-x));
}

__device__ __forceinline__ unsigned short f2bf_bits(float f) {
    bf16_t h = (bf16_t)f;
    unsigned short u;
    __builtin_memcpy(&u, &h, 2);
    return u;
}

__device__ __forceinline__ float bf_lo(unsigned int u) {
    return __uint_as_float(u << 16);
}
__device__ __forceinline__ float bf_hi(unsigned int u) {
    return __uint_as_float(u & 0xFFFF0000u);
}

// Fold BN into weights, transpose, cast bf16
__global__ void prep_w(const float* __restrict__ W, const float* __restrict__ gamma,
                       const float* __restrict__ beta, const float* __restrict__ mean,
                       const float* __restrict__ var, bf16_t* __restrict__ Wpt,
                       float* __restrict__ bp) {
    int l = blockIdx.x;
    int j = threadIdx.x;
    float acc = 0.f;
    for (int k = 0; k < D; ++k) {
        float a = gamma[l * D + k] * rsqrtf(var[l * D + k] + BN_EPS);
        float c = beta[l * D + k] - mean[l * D + k] * a;
        float w = W[l * D * D + k * D + j];
        Wpt[l * D * D + j * D + k] = (bf16_t)(a * w);
        acc = fmaf(c, w, acc);
    }
    bp[l * D + j] = acc;
}

// partitioned LDS histogram (no global atomics); 2 node ranges of 25000
__global__ __launch_bounds__(256) void count_part(const int* __restrict__ ei,
                                                  int* __restrict__ PR,
                                                  int* __restrict__ PC) {
    extern __shared__ int hist[];
    const int r = blockIdx.x, p = blockIdx.y, dirz = blockIdx.z;
    const int tid = threadIdx.x;
    for (int i = tid; i < RSZC; i += 256) hist[i] = 0;
    __syncthreads();
    const int base = r * RSZC;
    const int4* ids = (const int4*)(ei + dirz * NE + p * CSZ);
    for (int i = tid; i < CSZ / 4; i += 256) {
        int4 v = ids[i];
        int d0 = v.x - base, d1 = v.y - base, d2 = v.z - base, d3 = v.w - base;
        if ((unsigned)d0 < RSZC) atomicAdd(&hist[d0], 1);
        if ((unsigned)d1 < RSZC) atomicAdd(&hist[d1], 1);
        if ((unsigned)d2 < RSZC) atomicAdd(&hist[d2], 1);
        if ((unsigned)d3 < RSZC) atomicAdd(&hist[d3], 1);
    }
    __syncthreads();
    int* dst = (dirz == 0 ? PR : PC) + p * NNP + base;
    for (int i = tid; i < RSZC; i += 256) dst[i] = hist[i];
}

// fused: rowsum->dis, colscan->cnt + per-chunk offsets in PC, block-local scan1
__global__ void csr_mid(const int* __restrict__ PR, int* __restrict__ PC,
                        float* __restrict__ dis, int* __restrict__ cnt,
                        int* __restrict__ colp, int* __restrict__ bsum) {
    __shared__ int s[256];
    int t = threadIdx.x;
    int i = blockIdx.x * 256 + t;
    int run = 0;
    if (i < NN) {
        int dg = 0;
#pragma unroll 8
        for (int k = 0; k < NCHUNK; ++k) dg += PR[k * NNP + i];
        dis[i] = rsqrtf((float)(dg + 1));
        for (int k = 0; k < NCHUNK; ++k) {
            int v = PC[k * NNP + i];
            PC[k * NNP + i] = run;
            run += v;
        }
        cnt[i] = run;
    }
    s[t] = run;
    __syncthreads();
    for (int o = 1; o < 256; o <<= 1) {
        int add = (t >= o) ? s[t - o] : 0;
        __syncthreads();
        s[t] += add;
        __syncthreads();
    }
    if (i < NN) colp[i] = s[t] - run;  // local exclusive
    if (t == 255) bsum[blockIdx.x] = s[255];
}

__global__ void scan2(const int* __restrict__ bsum, int* __restrict__ boff, int nb) {
    __shared__ int s[256];
    int t = threadIdx.x;
    int v = (t < nb) ? bsum[t] : 0;
    s[t] = v;
    __syncthreads();
    for (int o = 1; o < 256; o <<= 1) {
        int add = (t >= o) ? s[t - o] : 0;
        __syncthreads();
        s[t] += add;
        __syncthreads();
    }
    boff[t] = s[t] - v;
}

__global__ void scan3(int* __restrict__ colp, const int* __restrict__ boff,
                      const int* __restrict__ cnt, int* __restrict__ ends) {
    int i = blockIdx.x * 256 + threadIdx.x;
    if (i < NN) {
        int v = colp[i] + boff[i >> 8];
        colp[i] = v;
        ends[i] = v + cnt[i];
    }
}

// atomic-free(global) CSR fill; 4 node ranges of 12500 (CPS is per-node)
__global__ __launch_bounds__(256) void fill_part(const int* __restrict__ ei,
                                                 const int* __restrict__ colp,
                                                 const int* __restrict__ CPS,
                                                 int* __restrict__ srcs) {
    __shared__ int curs[RSZF];
    const int r = blockIdx.x, p = blockIdx.y;
    const int tid = threadIdx.x;
    const int base = r * RSZF;
    for (int i = tid; i < RSZF; i += 256)
        curs[i] = colp[base + i] + CPS[p * NNP + base + i];
    __syncthreads();
    const int4* rows = (const int4*)(ei + p * CSZ);
    const int4* cols = (const int4*)(ei + NE + p * CSZ);
    for (int i = tid; i < CSZ / 4; i += 256) {
        int4 rv = rows[i];
        int4 cv = cols[i];
        int d;
        d = cv.x - base; if ((unsigned)d < RSZF) srcs[atomicAdd(&curs[d], 1)] = rv.x;
        d = cv.y - base; if ((unsigned)d < RSZF) srcs[atomicAdd(&curs[d], 1)] = rv.y;
        d = cv.z - base; if ((unsigned)d < RSZF) srcs[atomicAdd(&curs[d], 1)] = rv.z;
        d = cv.w - base; if ((unsigned)d < RSZF) srcs[atomicAdd(&curs[d], 1)] = rv.w;
    }
}

// MFMA bf16 GEMM: out[NNx128] = act(A[NNx128] @ B + bias). Bt is col-major bf16.
template <int AMODE, bool ORELU>
__global__ __launch_bounds__(256) void gemm_mfma(const void* __restrict__ Aptr,
                                                 const bf16_t* __restrict__ Bt,
                                                 const float* __restrict__ bias,
                                                 bf16_t* __restrict__ out) {
    const int tid = threadIdx.x;
    const int wv = tid >> 6;
    const int lane = tid & 63;
    const int l15 = lane & 15;
    const int l4 = lane >> 4;
    const int row0 = blockIdx.x * 64 + wv * 16;

    bf16x8 afrag[4];
    {
        int r = row0 + l15;
        int rc = (r < NN) ? r : (NN - 1);
#pragma unroll
        for (int kk = 0; kk < 4; ++kk) {
            int off = rc * D + kk * 32 + l4 * 8;
            if (AMODE == 0) {
                const float* A = (const float*)Aptr;
                float4 f0 = *(const float4*)(A + off);
                float4 f1 = *(const float4*)(A + off + 4);
                bf16x8 a;
                a[0] = (bf16_t)f0.x; a[1] = (bf16_t)f0.y;
                a[2] = (bf16_t)f0.z; a[3] = (bf16_t)f0.w;
                a[4] = (bf16_t)f1.x; a[5] = (bf16_t)f1.y;
                a[6] = (bf16_t)f1.z; a[7] = (bf16_t)f1.w;
                afrag[kk] = a;
            } else {
                const bf16_t* A = (const bf16_t*)Aptr;
                afrag[kk] = *(const bf16x8*)(A + off);
            }
        }
    }

    f32x4 acc[8];
#pragma unroll
    for (int n = 0; n < 8; ++n) acc[n] = (f32x4){0.f, 0.f, 0.f, 0.f};

#pragma unroll
    for (int n = 0; n < 8; ++n) {
#pragma unroll
        for (int kk = 0; kk < 4; ++kk) {
            bf16x8 bfrag = *(const bf16x8*)(Bt + (n * 16 + l15) * D + kk * 32 + l4 * 8);
            acc[n] = __builtin_amdgcn_mfma_f32_16x16x32_bf16(afrag[kk], bfrag, acc[n], 0, 0, 0);
        }
    }

#pragma unroll
    for (int n = 0; n < 8; ++n) {
        int col = n * 16 + l15;
        float bv = bias[col];
#pragma unroll
        for (int r = 0; r < 4; ++r) {
            int row = row0 + l4 * 4 + r;
            if (row < NN) {
                float v = acc[n][r] + bv;
                if (ORELU) v = fmaxf(v, 0.f);
                out[(size_t)row * D + col] = (bf16_t)v;
            }
        }
    }
}

// gather-form GCN propagate, one wave per destination node, unroll x8 w/ masking.
// POST 0: out bf16 = relu(v + bias);  POST 1: out fp32 = v
template <int POST>
__global__ __launch_bounds__(256) void prop_gather(
    const int* __restrict__ colp, const int* __restrict__ ends,
    const int* __restrict__ srcs, const float* __restrict__ dis,
    const bf16_t* __restrict__ hin, void* __restrict__ hout,
    const float* __restrict__ bias) {
    int n = blockIdx.x * 4 + (threadIdx.x >> 6);
    n = __builtin_amdgcn_readfirstlane(n);   // wave-uniform: scalarize CSR chain
    int lane = threadIdx.x & 63;
    if (n >= NN) return;
    const int start = colp[n];
    const int end = ends[n];
    const float dn = dis[n];
    unsigned int u = ((const unsigned int*)(hin + (size_t)n * D))[lane];
    float ax = dn * bf_lo(u), ay = dn * bf_hi(u);
    for (int i = start; i < end; i += 8) {
        float w_[8];
        unsigned int u_[8];
#pragma unroll
        for (int j = 0; j < 8; ++j) {
            int idx = i + j;
            bool ok = idx < end;
            int sj = srcs[ok ? idx : start];
            w_[j] = ok ? dis[sj] : 0.f;
            u_[j] = ((const unsigned int*)(hin + (size_t)sj * D))[lane];
        }
#pragma unroll
        for (int j = 0; j < 8; ++j) {
            ax = fmaf(w_[j], bf_lo(u_[j]), ax);
            ay = fmaf(w_[j], bf_hi(u_[j]), ay);
        }
    }
    float vx = dn * ax, vy = dn * ay;
    if (POST == 0) {
        float2 bb = ((const float2*)bias)[lane];
        vx = fmaxf(vx + bb.x, 0.f);
        vy = fmaxf(vy + bb.y, 0.f);
        unsigned int pk = (unsigned int)f2bf_bits(vx) | ((unsigned int)f2bf_bits(vy) << 16);
        ((unsigned int*)((bf16_t*)hout + (size_t)n * D))[lane] = pk;
    } else {
        ((float2*)((float*)hout + (size_t)n * D))[lane] = make_float2(vx, vy);
    }
}

// node head: 2 nodes per wave (32-lane groups, float4 per lane)
__global__ __launch_bounds__(256) void node_kernel(
    const float* __restrict__ h, const float* __restrict__ bh1,
    const float* __restrict__ We, const float* __restrict__ Wn,
    const float* __restrict__ bnb, const int* __restrict__ batch,
    float* __restrict__ nkey_out, float* __restrict__ t1, float* __restrict__ t2,
    float* __restrict__ accN) {
    __shared__ float binK[NG], binE[NG], binZ[NG], binC[NG];
    const int tid = threadIdx.x;
    for (int i = tid; i < NG; i += 256) { binK[i] = 0.f; binE[i] = 0.f; binZ[i] = 0.f; binC[i] = 0.f; }
    __syncthreads();

    const int CHUNK = 98;
    int start = blockIdx.x * CHUNK;
    int end = min(start + CHUNK, NN);
    int sub = tid >> 5;        // 0..7 : which 32-lane group
    int l32 = tid & 31;
    float bnb0 = bnb[0];

    float4 w1 = ((const float4*)We)[l32];
    float4 w2 = ((const float4*)(We + D))[l32];
    float4 wn = ((const float4*)Wn)[l32];
    float4 bb = ((const float4*)bh1)[l32];

    for (int n = start + sub; n < end; n += 8) {
        float4 v = ((const float4*)(h + (size_t)n * D))[l32];
        v.x += bb.x; v.y += bb.y; v.z += bb.z; v.w += bb.w;
        float s1 = v.x * w1.x + v.y * w1.y + v.z * w1.z + v.w * w1.w;
        float s2 = v.x * w2.x + v.y * w2.y + v.z * w2.z + v.w * w2.w;
        float s3 = v.x * wn.x + v.y * wn.y + v.z * wn.z + v.w * wn.w;
        for (int o = 16; o; o >>= 1) {
            s1 += __shfl_xor(s1, o);
            s2 += __shfl_xor(s2, o);
            s3 += __shfl_xor(s3, o);
        }
        if (l32 == 0) {
            t1[n] = s1;
            t2[n] = s2;
            float nk = sigmoidf(s3 + bnb0);
            nkey_out[n] = nk;
            int g = batch[n];
            atomicAdd(&binK[g], nk);
            atomicAdd(&binE[g], 1.0f - nk);
            if (nk > 0.f) atomicAdd(&binZ[g], 1.0f);
            atomicAdd(&binC[g], 1.0f);
        }
    }
    __syncthreads();
    if (start < NN) {
        int glo = batch[start];
        int ghi = batch[end - 1];
        for (int g = glo + tid; g <= ghi; g += 256) {
            unsafeAtomicAdd(&accN[g], binK[g]);
            unsafeAtomicAdd(&accN[NG + g], binE[g]);
            unsafeAtomicAdd(&accN[2 * NG + g], binZ[g]);
            unsafeAtomicAdd(&accN[3 * NG + g], binC[g]);
        }
    }
}

// edge head: 4 edges per thread via int4
__global__ __launch_bounds__(256) void edge_kernel(
    const int* __restrict__ ei, const float* __restrict__ t1,
    const float* __restrict__ t2, const float* __restrict__ be,
    const int* __restrict__ batch, float* __restrict__ ekey_out,
    float* __restrict__ accE) {
    __shared__ float binK[NG], binE[NG], binZ[NG], binC[NG];
    const int tid = threadIdx.x;
    for (int i = tid; i < NG; i += 256) { binK[i] = 0.f; binE[i] = 0.f; binZ[i] = 0.f; binC[i] = 0.f; }
    __syncthreads();
    float be0 = be[0];
    int stride4 = gridDim.x * 256;
    for (int q = blockIdx.x * 256 + tid; q < NE / 4; q += stride4) {
        int4 r4 = ((const int4*)ei)[q];
        int4 c4 = ((const int4*)(ei + NE))[q];
        float a0 = t1[r4.x], a1 = t1[r4.y], a2 = t1[r4.z], a3 = t1[r4.w];
        float b0 = t2[c4.x], b1 = t2[c4.y], b2 = t2[c4.z], b3 = t2[c4.w];
        int g0 = batch[r4.x], g1 = batch[r4.y], g2 = batch[r4.z], g3 = batch[r4.w];
        float e0 = sigmoidf(a0 + b0 + be0);
        float e1 = sigmoidf(a1 + b1 + be0);
        float e2 = sigmoidf(a2 + b2 + be0);
        float e3 = sigmoidf(a3 + b3 + be0);
        ((float4*)ekey_out)[q] = make_float4(e0, e1, e2, e3);
        atomicAdd(&binK[g0], e0); atomicAdd(&binE[g0], 1.0f - e0);
        if (e0 > 0.f) atomicAdd(&binZ[g0], 1.0f);
        atomicAdd(&binC[g0], 1.0f);
        atomicAdd(&binK[g1], e1); atomicAdd(&binE[g1], 1.0f - e1);
        if (e1 > 0.f) atomicAdd(&binZ[g1], 1.0f);
        atomicAdd(&binC[g1], 1.0f);
        atomicAdd(&binK[g2], e2); atomicAdd(&binE[g2], 1.0f - e2);
        if (e2 > 0.f) atomicAdd(&binZ[g2], 1.0f);
        atomicAdd(&binC[g2], 1.0f);
        atomicAdd(&binK[g3], e3); atomicAdd(&binE[g3], 1.0f - e3);
        if (e3 > 0.f) atomicAdd(&binZ[g3], 1.0f);
        atomicAdd(&binC[g3], 1.0f);
    }
    __syncthreads();
    for (int g = tid; g < NG; g += 256) {
        if (binC[g] != 0.f) {
            unsafeAtomicAdd(&accE[g], binK[g]);
            unsafeAtomicAdd(&accE[NG + g], binE[g]);
            unsafeAtomicAdd(&accE[2 * NG + g], binZ[g]);
            unsafeAtomicAdd(&accE[3 * NG + g], binC[g]);
        }
    }
}

__global__ void final_kernel(const float* __restrict__ accN,
                             const float* __restrict__ accE,
                             float* __restrict__ out) {
    int g = blockIdx.x * 256 + threadIdx.x;
    if (g < NG) {
        out[O_NKN + g] = accN[g] + 1e-8f;
        out[O_NEN + g] = accN[NG + g] + 1e-8f;
        out[O_EKN + g] = accE[g] + 1e-8f;
        out[O_EEN + g] = accE[NG + g] + 1e-8f;
        out[O_NZN + g] = accN[2 * NG + g] / accN[3 * NG + g];
        out[O_NZE + g] = accE[2 * NG + g] / accE[3 * NG + g];
    }
}

extern "C" void kernel_launch(void* const* d_in, const int* in_sizes, int n_in,
                              void* d_out, int out_size, void* d_ws, size_t ws_size,
                              hipStream_t stream) {
    const float* x     = (const float*)d_in[0];
    const int*   ei    = (const int*)d_in[1];
    const int*   batch = (const int*)d_in[2];
    const float* W     = (const float*)d_in[4];
    const float* bh    = (const float*)d_in[5];   // [2][128]
    const float* gamma = (const float*)d_in[6];
    const float* beta  = (const float*)d_in[7];
    const float* mean  = (const float*)d_in[8];
    const float* var   = (const float*)d_in[9];
    const float* We    = (const float*)d_in[10];
    const float* be    = (const float*)d_in[11];
    const float* Wn    = (const float*)d_in[12];
    const float* bnb   = (const float*)d_in[13];

    float* ws  = (float*)d_ws;
    float* out = (float*)d_out;

    float*  accN = ws + OFF_ACCN;
    float*  accE = ws + OFF_ACCE;
    float*  dis  = ws + OFF_DIS;
    int*    cnt  = (int*)(ws + OFF_CNT);
    int*    colp = (int*)(ws + OFF_COLP);
    int*    ends = (int*)(ws + OFF_ENDS);
    int*    bsum = (int*)(ws + OFF_BSUM);
    int*    boff = (int*)(ws + OFF_BOFF);
    float*  t1   = ws + OFF_T1;
    float*  t2   = ws + OFF_T2;
    float*  bp   = ws + OFF_BP;
    bf16_t* Wpt  = (bf16_t*)(ws + OFF_WPT);
    int*    PR   = (int*)(ws + OFF_PR);
    int*    PC   = (int*)(ws + OFF_PC);
    int*    srcs = (int*)(ws + OFF_SRCS);
    bf16_t* hbfA = (bf16_t*)(ws + OFF_HBFA);
    bf16_t* hbfB = (bf16_t*)(ws + OFF_HBFB);
    float*  hA32 = ws + OFF_HA32;   // aliases PR/PC (dead after fill_part)

    hipMemsetAsync(d_ws, 0, (size_t)ZERO_FLOATS * sizeof(float), stream);

    prep_w<<<3, 128, 0, stream>>>(W, gamma, beta, mean, var, Wpt, bp);

    // ---- atomic-free CSR build ----
    count_part<<<dim3(2, NCHUNK, 2), 256, RSZC * sizeof(int), stream>>>(ei, PR, PC);
    const int NB = (NN + 255) / 256;  // 196
    csr_mid<<<NB, 256, 0, stream>>>(PR, PC, dis, cnt, colp, bsum);
    scan2<<<1, 256, 0, stream>>>(bsum, boff, NB);
    scan3<<<NB, 256, 0, stream>>>(colp, boff, cnt, ends);
    fill_part<<<dim3(4, NCHUNK), 256, 0, stream>>>(ei, colp, PC, srcs);

    const int GB = (NN + 63) / 64;  // 782
    // layer 0: hbfA = bf16(relu(x @ Wp0 + bp0))
    gemm_mfma<0, true><<<GB, 256, 0, stream>>>(x, Wpt, bp, hbfA);
    // layer 1 linear: hbfB = bf16(hbfA @ Wp1 + bp1)
    gemm_mfma<1, false><<<GB, 256, 0, stream>>>(hbfA, Wpt + D * D, bp + D, hbfB);
    // propagate 1 + fused relu(v + bh0): hbfA = bf16(relu(P(hbfB) + bh0))
    prop_gather<0><<<12500, 256, 0, stream>>>(colp, ends, srcs, dis, hbfB, hbfA, bh);
    // layer 2 linear: hbfB = bf16(hbfA @ Wp2 + bp2)
    gemm_mfma<1, false><<<GB, 256, 0, stream>>>(hbfA, Wpt + 2 * D * D, bp + 2 * D, hbfB);
    // propagate 2: hA32 = P(hbfB)  (fp32 for heads; PR/PC space reused)
    prop_gather<1><<<12500, 256, 0, stream>>>(colp, ends, srcs, dis, hbfB, hA32, nullptr);

    node_kernel<<<512, 256, 0, stream>>>(hA32, bh + D, We, Wn, bnb, batch,
                                         out + O_NKEY, t1, t2, accN);
    edge_kernel<<<256, 256, 0, stream>>>(ei, t1, t2, be, batch, out + O_EKEY, accE);
    final_kernel<<<2, 256, 0, stream>>>(accN, accE, out);
}

// Round 7
// 255.192 us; speedup vs baseline: 1.0628x; 1.0628x over previous
//
#include <hip/hip_runtime.h>
#include <cstddef>
#include <cstring>

#define NN 50000
#define NNP 50048
#define NE 800000
#define D 128
#define NG 512
#define BN_EPS 1e-5f
#define RSZC 25000    // count: nodes per range (2 ranges, 100 KB dyn LDS)
#define RSZF 12500    // fill: nodes per range (4 ranges, 50 KB LDS)
#define NCHUNK 64
#define CSZ 12500     // edges per chunk

typedef __bf16 bf16_t;
typedef __bf16 bf16x8 __attribute__((ext_vector_type(8)));
typedef float f32x4 __attribute__((ext_vector_type(4)));

// ---- workspace layout (float offsets) ----
#define OFF_ACCN 0            // float[4*512]
#define OFF_ACCE 2048         // float[4*512]
#define ZERO_FLOATS 4096      // only the accumulators need zeroing
#define OFF_DIS  4096         // float[50048]
#define OFF_CNT  54144        // int[50048]
#define OFF_COLP 104192       // int[50048]
#define OFF_ENDS 154240       // int[50048]
#define OFF_BSUM 204288       // int[256]
#define OFF_BOFF 204544       // int[256]
#define OFF_T1   204800       // float[50048]
#define OFF_T2   254848       // float[50048]
#define OFF_BP   304896       // float[3*128 padded]
#define OFF_WPT  305408       // bf16[3*128*128] (24576 floats)
#define OFF_PR   329984       // int[64][50048] = 3203072
#define OFF_PC   3533056      // int[64][50048] = 3203072 (CPS after csr_mid)
#define OFF_SRCS2 OFF_PR      // int2[800000] = 1600000 ints, aliases PR (dead after csr_mid)
#define OFF_HBFA 7536128      // bf16[50048*128] (3203072 floats)
#define OFF_HBFB 10739200     // bf16[50048*128]

// ---- output layout (float offsets in d_out) ----
#define O_NKEY 0
#define O_EKEY 50000
#define O_NKN  850000
#define O_NEN  850512
#define O_EKN  851024
#define O_EEN  851536
#define O_NZN  852048
#define O_NZE  852560

__device__ __forceinline__ float sigmoidf(float x) {
    return 1.0f / (1.0f + expf(-x));
}

__device__ __forceinline__ unsigned short f2bf_bits(float f) {
    bf16_t h = (bf16_t)f;
    unsigned short u;
    __builtin_memcpy(&u, &h, 2);
    return u;
}

__device__ __forceinline__ float bf_lo(unsigned int u) {
    return __uint_as_float(u << 16);
}
__device__ __forceinline__ float bf_hi(unsigned int u) {
    return __uint_as_float(u & 0xFFFF0000u);
}

// Fold BN into weights, transpose, cast bf16
__global__ void prep_w(const float* __restrict__ W, const float* __restrict__ gamma,
                       const float* __restrict__ beta, const float* __restrict__ mean,
                       const float* __restrict__ var, bf16_t* __restrict__ Wpt,
                       float* __restrict__ bp) {
    int l = blockIdx.x;
    int j = threadIdx.x;
    float acc = 0.f;
    for (int k = 0; k < D; ++k) {
        float a = gamma[l * D + k] * rsqrtf(var[l * D + k] + BN_EPS);
        float c = beta[l * D + k] - mean[l * D + k] * a;
        float w = W[l * D * D + k * D + j];
        Wpt[l * D * D + j * D + k] = (bf16_t)(a * w);
        acc = fmaf(c, w, acc);
    }
    bp[l * D + j] = acc;
}

// partitioned LDS histogram (no global atomics); 2 node ranges of 25000
__global__ __launch_bounds__(256) void count_part(const int* __restrict__ ei,
                                                  int* __restrict__ PR,
                                                  int* __restrict__ PC) {
    extern __shared__ int hist[];
    const int r = blockIdx.x, p = blockIdx.y, dirz = blockIdx.z;
    const int tid = threadIdx.x;
    for (int i = tid; i < RSZC; i += 256) hist[i] = 0;
    __syncthreads();
    const int base = r * RSZC;
    const int4* ids = (const int4*)(ei + dirz * NE + p * CSZ);
    for (int i = tid; i < CSZ / 4; i += 256) {
        int4 v = ids[i];
        int d0 = v.x - base, d1 = v.y - base, d2 = v.z - base, d3 = v.w - base;
        if ((unsigned)d0 < RSZC) atomicAdd(&hist[d0], 1);
        if ((unsigned)d1 < RSZC) atomicAdd(&hist[d1], 1);
        if ((unsigned)d2 < RSZC) atomicAdd(&hist[d2], 1);
        if ((unsigned)d3 < RSZC) atomicAdd(&hist[d3], 1);
    }
    __syncthreads();
    int* dst = (dirz == 0 ? PR : PC) + p * NNP + base;
    for (int i = tid; i < RSZC; i += 256) dst[i] = hist[i];
}

// fused: rowsum->dis, colscan->cnt + per-chunk offsets in PC, block-local scan1
__global__ void csr_mid(const int* __restrict__ PR, int* __restrict__ PC,
                        float* __restrict__ dis, int* __restrict__ cnt,
                        int* __restrict__ colp, int* __restrict__ bsum) {
    __shared__ int s[256];
    int t = threadIdx.x;
    int i = blockIdx.x * 256 + t;
    int run = 0;
    if (i < NN) {
        int dg = 0;
#pragma unroll 8
        for (int k = 0; k < NCHUNK; ++k) dg += PR[k * NNP + i];
        dis[i] = rsqrtf((float)(dg + 1));
        for (int k = 0; k < NCHUNK; ++k) {
            int v = PC[k * NNP + i];
            PC[k * NNP + i] = run;
            run += v;
        }
        cnt[i] = run;
    }
    s[t] = run;
    __syncthreads();
    for (int o = 1; o < 256; o <<= 1) {
        int add = (t >= o) ? s[t - o] : 0;
        __syncthreads();
        s[t] += add;
        __syncthreads();
    }
    if (i < NN) colp[i] = s[t] - run;  // local exclusive
    if (t == 255) bsum[blockIdx.x] = s[255];
}

__global__ void scan2(const int* __restrict__ bsum, int* __restrict__ boff, int nb) {
    __shared__ int s[256];
    int t = threadIdx.x;
    int v = (t < nb) ? bsum[t] : 0;
    s[t] = v;
    __syncthreads();
    for (int o = 1; o < 256; o <<= 1) {
        int add = (t >= o) ? s[t - o] : 0;
        __syncthreads();
        s[t] += add;
        __syncthreads();
    }
    boff[t] = s[t] - v;
}

__global__ void scan3(int* __restrict__ colp, const int* __restrict__ boff,
                      const int* __restrict__ cnt, int* __restrict__ ends) {
    int i = blockIdx.x * 256 + threadIdx.x;
    if (i < NN) {
        int v = colp[i] + boff[i >> 8];
        colp[i] = v;
        ends[i] = v + cnt[i];
    }
}

// atomic-free(global) CSR fill; writes (src, dis[src]) pairs so the gather
// needs no dependent dis load. 4 node ranges of 12500.
__global__ __launch_bounds__(256) void fill_part(const int* __restrict__ ei,
                                                 const int* __restrict__ colp,
                                                 const int* __restrict__ CPS,
                                                 const float* __restrict__ dis,
                                                 int2* __restrict__ srcs2) {
    __shared__ int curs[RSZF];
    const int r = blockIdx.x, p = blockIdx.y;
    const int tid = threadIdx.x;
    const int base = r * RSZF;
    for (int i = tid; i < RSZF; i += 256)
        curs[i] = colp[base + i] + CPS[p * NNP + base + i];
    __syncthreads();
    const int4* rows = (const int4*)(ei + p * CSZ);
    const int4* cols = (const int4*)(ei + NE + p * CSZ);
    for (int i = tid; i < CSZ / 4; i += 256) {
        int4 rv = rows[i];
        int4 cv = cols[i];
        int d;
        d = cv.x - base;
        if ((unsigned)d < RSZF)
            srcs2[atomicAdd(&curs[d], 1)] = make_int2(rv.x, __float_as_int(dis[rv.x]));
        d = cv.y - base;
        if ((unsigned)d < RSZF)
            srcs2[atomicAdd(&curs[d], 1)] = make_int2(rv.y, __float_as_int(dis[rv.y]));
        d = cv.z - base;
        if ((unsigned)d < RSZF)
            srcs2[atomicAdd(&curs[d], 1)] = make_int2(rv.z, __float_as_int(dis[rv.z]));
        d = cv.w - base;
        if ((unsigned)d < RSZF)
            srcs2[atomicAdd(&curs[d], 1)] = make_int2(rv.w, __float_as_int(dis[rv.w]));
    }
}

// MFMA bf16 GEMM: out[NNx128] = act(A[NNx128] @ B + bias). Bt is col-major bf16.
template <int AMODE, bool ORELU>
__global__ __launch_bounds__(256) void gemm_mfma(const void* __restrict__ Aptr,
                                                 const bf16_t* __restrict__ Bt,
                                                 const float* __restrict__ bias,
                                                 bf16_t* __restrict__ out) {
    const int tid = threadIdx.x;
    const int wv = tid >> 6;
    const int lane = tid & 63;
    const int l15 = lane & 15;
    const int l4 = lane >> 4;
    const int row0 = blockIdx.x * 64 + wv * 16;

    bf16x8 afrag[4];
    {
        int r = row0 + l15;
        int rc = (r < NN) ? r : (NN - 1);
#pragma unroll
        for (int kk = 0; kk < 4; ++kk) {
            int off = rc * D + kk * 32 + l4 * 8;
            if (AMODE == 0) {
                const float* A = (const float*)Aptr;
                float4 f0 = *(const float4*)(A + off);
                float4 f1 = *(const float4*)(A + off + 4);
                bf16x8 a;
                a[0] = (bf16_t)f0.x; a[1] = (bf16_t)f0.y;
                a[2] = (bf16_t)f0.z; a[3] = (bf16_t)f0.w;
                a[4] = (bf16_t)f1.x; a[5] = (bf16_t)f1.y;
                a[6] = (bf16_t)f1.z; a[7] = (bf16_t)f1.w;
                afrag[kk] = a;
            } else {
                const bf16_t* A = (const bf16_t*)Aptr;
                afrag[kk] = *(const bf16x8*)(A + off);
            }
        }
    }

    f32x4 acc[8];
#pragma unroll
    for (int n = 0; n < 8; ++n) acc[n] = (f32x4){0.f, 0.f, 0.f, 0.f};

#pragma unroll
    for (int n = 0; n < 8; ++n) {
#pragma unroll
        for (int kk = 0; kk < 4; ++kk) {
            bf16x8 bfrag = *(const bf16x8*)(Bt + (n * 16 + l15) * D + kk * 32 + l4 * 8);
            acc[n] = __builtin_amdgcn_mfma_f32_16x16x32_bf16(afrag[kk], bfrag, acc[n], 0, 0, 0);
        }
    }

#pragma unroll
    for (int n = 0; n < 8; ++n) {
        int col = n * 16 + l15;
        float bv = bias[col];
#pragma unroll
        for (int r = 0; r < 4; ++r) {
            int row = row0 + l4 * 4 + r;
            if (row < NN) {
                float v = acc[n][r] + bv;
                if (ORELU) v = fmaxf(v, 0.f);
                out[(size_t)row * D + col] = (bf16_t)v;
            }
        }
    }
}

// gather-form GCN propagate, one wave per destination node, unroll x4.
// srcs2 = (src, dis[src]) pairs -> no dependent dis load.
// POST 0: out bf16 = relu(v + bias);  POST 1: out bf16 = v
template <int POST>
__global__ __launch_bounds__(256) void prop_gather(
    const int* __restrict__ colp, const int* __restrict__ ends,
    const int2* __restrict__ srcs2, const float* __restrict__ dis,
    const bf16_t* __restrict__ hin, bf16_t* __restrict__ hout,
    const float* __restrict__ bias) {
    int n = blockIdx.x * 4 + (threadIdx.x >> 6);
    n = __builtin_amdgcn_readfirstlane(n);   // wave-uniform: scalarize CSR chain
    int lane = threadIdx.x & 63;
    if (n >= NN) return;
    const int start = colp[n];
    const int end = ends[n];
    const float dn = dis[n];
    unsigned int u = ((const unsigned int*)(hin + (size_t)n * D))[lane];
    float ax = dn * bf_lo(u), ay = dn * bf_hi(u);
    int i = start;
    for (; i + 3 < end; i += 4) {
        int2 e0 = srcs2[i], e1 = srcs2[i + 1], e2 = srcs2[i + 2], e3 = srcs2[i + 3];
        unsigned int u0 = ((const unsigned int*)(hin + (size_t)e0.x * D))[lane];
        unsigned int u1 = ((const unsigned int*)(hin + (size_t)e1.x * D))[lane];
        unsigned int u2 = ((const unsigned int*)(hin + (size_t)e2.x * D))[lane];
        unsigned int u3 = ((const unsigned int*)(hin + (size_t)e3.x * D))[lane];
        float w0 = __int_as_float(e0.y), w1 = __int_as_float(e1.y);
        float w2 = __int_as_float(e2.y), w3 = __int_as_float(e3.y);
        ax = fmaf(w0, bf_lo(u0), ax); ay = fmaf(w0, bf_hi(u0), ay);
        ax = fmaf(w1, bf_lo(u1), ax); ay = fmaf(w1, bf_hi(u1), ay);
        ax = fmaf(w2, bf_lo(u2), ax); ay = fmaf(w2, bf_hi(u2), ay);
        ax = fmaf(w3, bf_lo(u3), ax); ay = fmaf(w3, bf_hi(u3), ay);
    }
    for (; i < end; ++i) {
        int2 e0 = srcs2[i];
        unsigned int u0 = ((const unsigned int*)(hin + (size_t)e0.x * D))[lane];
        float w0 = __int_as_float(e0.y);
        ax = fmaf(w0, bf_lo(u0), ax); ay = fmaf(w0, bf_hi(u0), ay);
    }
    float vx = dn * ax, vy = dn * ay;
    if (POST == 0) {
        float2 bb = ((const float2*)bias)[lane];
        vx = fmaxf(vx + bb.x, 0.f);
        vy = fmaxf(vy + bb.y, 0.f);
    }
    unsigned int pk = (unsigned int)f2bf_bits(vx) | ((unsigned int)f2bf_bits(vy) << 16);
    ((unsigned int*)(hout + (size_t)n * D))[lane] = pk;
}

// node head on bf16 node_rep: 2 nodes per wave (32-lane groups, 4 bf16/lane)
__global__ __launch_bounds__(256) void node_kernel(
    const bf16_t* __restrict__ h, const float* __restrict__ bh1,
    const float* __restrict__ We, const float* __restrict__ Wn,
    const float* __restrict__ bnb, const int* __restrict__ batch,
    float* __restrict__ nkey_out, float* __restrict__ t1, float* __restrict__ t2,
    float* __restrict__ accN) {
    __shared__ float binK[NG], binE[NG], binZ[NG], binC[NG];
    const int tid = threadIdx.x;
    for (int i = tid; i < NG; i += 256) { binK[i] = 0.f; binE[i] = 0.f; binZ[i] = 0.f; binC[i] = 0.f; }
    __syncthreads();

    const int CHUNK = 98;
    int start = blockIdx.x * CHUNK;
    int end = min(start + CHUNK, NN);
    int sub = tid >> 5;        // 0..7 : which 32-lane group
    int l32 = tid & 31;
    float bnb0 = bnb[0];

    float4 w1 = ((const float4*)We)[l32];
    float4 w2 = ((const float4*)(We + D))[l32];
    float4 wn = ((const float4*)Wn)[l32];
    float4 bb = ((const float4*)bh1)[l32];

    for (int n = start + sub; n < end; n += 8) {
        uint2 pk = ((const uint2*)(h + (size_t)n * D))[l32];
        float v0 = bf_lo(pk.x) + bb.x;
        float v1 = bf_hi(pk.x) + bb.y;
        float v2 = bf_lo(pk.y) + bb.z;
        float v3 = bf_hi(pk.y) + bb.w;
        float s1 = v0 * w1.x + v1 * w1.y + v2 * w1.z + v3 * w1.w;
        float s2 = v0 * w2.x + v1 * w2.y + v2 * w2.z + v3 * w2.w;
        float s3 = v0 * wn.x + v1 * wn.y + v2 * wn.z + v3 * wn.w;
        for (int o = 16; o; o >>= 1) {
            s1 += __shfl_xor(s1, o);
            s2 += __shfl_xor(s2, o);
            s3 += __shfl_xor(s3, o);
        }
        if (l32 == 0) {
            t1[n] = s1;
            t2[n] = s2;
            float nk = sigmoidf(s3 + bnb0);
            nkey_out[n] = nk;
            int g = batch[n];
            atomicAdd(&binK[g], nk);
            atomicAdd(&binE[g], 1.0f - nk);
            if (nk > 0.f) atomicAdd(&binZ[g], 1.0f);
            atomicAdd(&binC[g], 1.0f);
        }
    }
    __syncthreads();
    if (start < NN) {
        int glo = batch[start];
        int ghi = batch[end - 1];
        for (int g = glo + tid; g <= ghi; g += 256) {
            unsafeAtomicAdd(&accN[g], binK[g]);
            unsafeAtomicAdd(&accN[NG + g], binE[g]);
            unsafeAtomicAdd(&accN[2 * NG + g], binZ[g]);
            unsafeAtomicAdd(&accN[3 * NG + g], binC[g]);
        }
    }
}

// edge head: 4 edges per thread via int4
__global__ __launch_bounds__(256) void edge_kernel(
    const int* __restrict__ ei, const float* __restrict__ t1,
    const float* __restrict__ t2, const float* __restrict__ be,
    const int* __restrict__ batch, float* __restrict__ ekey_out,
    float* __restrict__ accE) {
    __shared__ float binK[NG], binE[NG], binZ[NG], binC[NG];
    const int tid = threadIdx.x;
    for (int i = tid; i < NG; i += 256) { binK[i] = 0.f; binE[i] = 0.f; binZ[i] = 0.f; binC[i] = 0.f; }
    __syncthreads();
    float be0 = be[0];
    int stride4 = gridDim.x * 256;
    for (int q = blockIdx.x * 256 + tid; q < NE / 4; q += stride4) {
        int4 r4 = ((const int4*)ei)[q];
        int4 c4 = ((const int4*)(ei + NE))[q];
        float a0 = t1[r4.x], a1 = t1[r4.y], a2 = t1[r4.z], a3 = t1[r4.w];
        float b0 = t2[c4.x], b1 = t2[c4.y], b2 = t2[c4.z], b3 = t2[c4.w];
        int g0 = batch[r4.x], g1 = batch[r4.y], g2 = batch[r4.z], g3 = batch[r4.w];
        float e0 = sigmoidf(a0 + b0 + be0);
        float e1 = sigmoidf(a1 + b1 + be0);
        float e2 = sigmoidf(a2 + b2 + be0);
        float e3 = sigmoidf(a3 + b3 + be0);
        ((float4*)ekey_out)[q] = make_float4(e0, e1, e2, e3);
        atomicAdd(&binK[g0], e0); atomicAdd(&binE[g0], 1.0f - e0);
        if (e0 > 0.f) atomicAdd(&binZ[g0], 1.0f);
        atomicAdd(&binC[g0], 1.0f);
        atomicAdd(&binK[g1], e1); atomicAdd(&binE[g1], 1.0f - e1);
        if (e1 > 0.f) atomicAdd(&binZ[g1], 1.0f);
        atomicAdd(&binC[g1], 1.0f);
        atomicAdd(&binK[g2], e2); atomicAdd(&binE[g2], 1.0f - e2);
        if (e2 > 0.f) atomicAdd(&binZ[g2], 1.0f);
        atomicAdd(&binC[g2], 1.0f);
        atomicAdd(&binK[g3], e3); atomicAdd(&binE[g3], 1.0f - e3);
        if (e3 > 0.f) atomicAdd(&binZ[g3], 1.0f);
        atomicAdd(&binC[g3], 1.0f);
    }
    __syncthreads();
    for (int g = tid; g < NG; g += 256) {
        if (binC[g] != 0.f) {
            unsafeAtomicAdd(&accE[g], binK[g]);
            unsafeAtomicAdd(&accE[NG + g], binE[g]);
            unsafeAtomicAdd(&accE[2 * NG + g], binZ[g]);
            unsafeAtomicAdd(&accE[3 * NG + g], binC[g]);
        }
    }
}

__global__ void final_kernel(const float* __restrict__ accN,
                             const float* __restrict__ accE,
                             float* __restrict__ out) {
    int g = blockIdx.x * 256 + threadIdx.x;
    if (g < NG) {
        out[O_NKN + g] = accN[g] + 1e-8f;
        out[O_NEN + g] = accN[NG + g] + 1e-8f;
        out[O_EKN + g] = accE[g] + 1e-8f;
        out[O_EEN + g] = accE[NG + g] + 1e-8f;
        out[O_NZN + g] = accN[2 * NG + g] / accN[3 * NG + g];
        out[O_NZE + g] = accE[2 * NG + g] / accE[3 * NG + g];
    }
}

extern "C" void kernel_launch(void* const* d_in, const int* in_sizes, int n_in,
                              void* d_out, int out_size, void* d_ws, size_t ws_size,
                              hipStream_t stream) {
    const float* x     = (const float*)d_in[0];
    const int*   ei    = (const int*)d_in[1];
    const int*   batch = (const int*)d_in[2];
    const float* W     = (const float*)d_in[4];
    const float* bh    = (const float*)d_in[5];   // [2][128]
    const float* gamma = (const float*)d_in[6];
    const float* beta  = (const float*)d_in[7];
    const float* mean  = (const float*)d_in[8];
    const float* var   = (const float*)d_in[9];
    const float* We    = (const float*)d_in[10];
    const float* be    = (const float*)d_in[11];
    const float* Wn    = (const float*)d_in[12];
    const float* bnb   = (const float*)d_in[13];

    float* ws  = (float*)d_ws;
    float* out = (float*)d_out;

    float*  accN  = ws + OFF_ACCN;
    float*  accE  = ws + OFF_ACCE;
    float*  dis   = ws + OFF_DIS;
    int*    cnt   = (int*)(ws + OFF_CNT);
    int*    colp  = (int*)(ws + OFF_COLP);
    int*    ends  = (int*)(ws + OFF_ENDS);
    int*    bsum  = (int*)(ws + OFF_BSUM);
    int*    boff  = (int*)(ws + OFF_BOFF);
    float*  t1    = ws + OFF_T1;
    float*  t2    = ws + OFF_T2;
    float*  bp    = ws + OFF_BP;
    bf16_t* Wpt   = (bf16_t*)(ws + OFF_WPT);
    int*    PR    = (int*)(ws + OFF_PR);
    int*    PC    = (int*)(ws + OFF_PC);
    int2*   srcs2 = (int2*)(ws + OFF_SRCS2);   // aliases PR (dead after csr_mid)
    bf16_t* hbfA  = (bf16_t*)(ws + OFF_HBFA);
    bf16_t* hbfB  = (bf16_t*)(ws + OFF_HBFB);

    hipMemsetAsync(d_ws, 0, (size_t)ZERO_FLOATS * sizeof(float), stream);

    prep_w<<<3, 128, 0, stream>>>(W, gamma, beta, mean, var, Wpt, bp);

    // ---- atomic-free CSR build ----
    count_part<<<dim3(2, NCHUNK, 2), 256, RSZC * sizeof(int), stream>>>(ei, PR, PC);
    const int NB = (NN + 255) / 256;  // 196
    csr_mid<<<NB, 256, 0, stream>>>(PR, PC, dis, cnt, colp, bsum);
    scan2<<<1, 256, 0, stream>>>(bsum, boff, NB);
    scan3<<<NB, 256, 0, stream>>>(colp, boff, cnt, ends);
    fill_part<<<dim3(4, NCHUNK), 256, 0, stream>>>(ei, colp, PC, dis, srcs2);

    const int GB = (NN + 63) / 64;  // 782
    // layer 0: hbfA = bf16(relu(x @ Wp0 + bp0))
    gemm_mfma<0, true><<<GB, 256, 0, stream>>>(x, Wpt, bp, hbfA);
    // layer 1 linear: hbfB = bf16(hbfA @ Wp1 + bp1)
    gemm_mfma<1, false><<<GB, 256, 0, stream>>>(hbfA, Wpt + D * D, bp + D, hbfB);
    // propagate 1 + fused relu(v + bh0): hbfA = bf16(relu(P(hbfB) + bh0))
    prop_gather<0><<<12500, 256, 0, stream>>>(colp, ends, srcs2, dis, hbfB, hbfA, bh);
    // layer 2 linear: hbfB = bf16(hbfA @ Wp2 + bp2)
    gemm_mfma<1, false><<<GB, 256, 0, stream>>>(hbfA, Wpt + 2 * D * D, bp + 2 * D, hbfB);
    // propagate 2: hbfA = bf16(P(hbfB))  (node_rep, bf16)
    prop_gather<1><<<12500, 256, 0, stream>>>(colp, ends, srcs2, dis, hbfB, hbfA, nullptr);

    node_kernel<<<512, 256, 0, stream>>>(hbfA, bh + D, We, Wn, bnb, batch,
                                         out + O_NKEY, t1, t2, accN);
    edge_kernel<<<256, 256, 0, stream>>>(ei, t1, t2, be, batch, out + O_EKEY, accE);
    final_kernel<<<2, 256, 0, stream>>>(accN, accE, out);
}